// Round 1
// baseline (290.325 us; speedup 1.0000x reference)
//
#include <hip/hip_runtime.h>
#include <math.h>

#define NB    32      // batch
#define NP    100     // points per image
#define IMH   1024
#define IMW   1024
#define CS    32      // crop size
#define OFFS  16
#define NTAP  33
#define C1c   0.0001f // 0.01^2
#define C2c   0.0009f // 0.03^2

struct GWin { float g[NTAP]; };

__global__ __launch_bounds__(256) void issim_crops(
    const float* __restrict__ outp,   // [B,1,H,W]
    const float* __restrict__ tgt,    // [B,1,H,W]
    const int*   __restrict__ pts,    // [B,P,2] (y,x)
    float* __restrict__ partial,      // [B*P] per-crop sums
    GWin gw)
{
    // crop staging with 16-col zero padding each side -> branch-free horiz pass
    __shared__ float tp[CS][64];
    __shared__ float op[CS][64];
    // horizontal conv results for the 5 channels (t, o, t*t, o*o, t*o)
    __shared__ float ht[CS][CS], ho[CS][CS], htt[CS][CS], hoo[CS][CS], hto[CS][CS];

    const int bp = blockIdx.x;            // crop id in [0, B*P)
    const int b  = bp / NP;
    const int y  = pts[bp * 2 + 0];
    const int x  = pts[bp * 2 + 1];
    const float* tb = tgt  + (size_t)b * IMH * IMW;
    const float* ob = outp + (size_t)b * IMH * IMW;

    const int tid = threadIdx.x;

    // ---- load crops (32x32 each) into padded LDS ----
#pragma unroll
    for (int k = 0; k < 8; ++k) {
        int idx = tid + k * 256;          // 0..2047 over [32][64]
        int r = idx >> 6, c = idx & 63;
        float tv = 0.f, ov = 0.f;
        if (c >= OFFS && c < OFFS + CS) {
            int gr = y - OFFS + r;
            int gc = x - OFFS + (c - OFFS);
            size_t a = (size_t)gr * IMW + gc;
            tv = tb[a];
            ov = ob[a];
        }
        tp[r][c] = tv;
        op[r][c] = ov;
    }
    __syncthreads();

    // ---- horizontal separable pass (5 channels, products on the fly) ----
#pragma unroll
    for (int k = 0; k < 4; ++k) {
        int f = tid + k * 256;            // 0..1023 over [32][32]
        int r = f >> 5, j = f & 31;
        float at = 0.f, ao = 0.f, att = 0.f, aoo = 0.f, ato = 0.f;
#pragma unroll
        for (int kj = 0; kj < NTAP; ++kj) {
            float w  = gw.g[kj];
            float tv = tp[r][j + kj];
            float ov = op[r][j + kj];
            at  += w * tv;
            ao  += w * ov;
            att += w * tv * tv;
            aoo += w * ov * ov;
            ato += w * tv * ov;
        }
        ht[r][j]  = at;
        ho[r][j]  = ao;
        htt[r][j] = att;
        hoo[r][j] = aoo;
        hto[r][j] = ato;
    }
    __syncthreads();

    // ---- vertical pass + SSIM + per-thread accumulation ----
    float lsum = 0.f;
#pragma unroll
    for (int k = 0; k < 4; ++k) {
        int f = tid + k * 256;
        int i = f >> 5, j = f & 31;
        // valid taps: rows i-16+ki in [0,32)
        int klo = OFFS - i;       if (klo < 0)    klo = 0;
        int khi = OFFS + CS - i;  if (khi > NTAP) khi = NTAP;
        float at = 0.f, ao = 0.f, att = 0.f, aoo = 0.f, ato = 0.f;
        for (int ki = klo; ki < khi; ++ki) {
            int r = i - OFFS + ki;
            float w = gw.g[ki];
            at  += w * ht[r][j];
            ao  += w * ho[r][j];
            att += w * htt[r][j];
            aoo += w * hoo[r][j];
            ato += w * hto[r][j];
        }
        float mu1  = at, mu2 = ao;
        float mu1s = mu1 * mu1, mu2s = mu2 * mu2, mu12 = mu1 * mu2;
        float s1   = att - mu1s;
        float s2   = aoo - mu2s;
        float s12  = ato - mu12;
        float num  = (2.f * mu12 + C1c) * (2.f * s12 + C2c);
        float den  = (mu1s + mu2s + C1c) * (s1 + s2 + C2c);
        lsum += 1.f - num / den;
    }

    // ---- block reduction: 64-lane shuffle, then across 4 waves via LDS ----
#pragma unroll
    for (int d = 32; d > 0; d >>= 1) lsum += __shfl_down(lsum, d, 64);
    __shared__ float wsum[4];
    int wid = tid >> 6, lane = tid & 63;
    if (lane == 0) wsum[wid] = lsum;
    __syncthreads();
    if (tid == 0) partial[bp] = wsum[0] + wsum[1] + wsum[2] + wsum[3];
}

__global__ __launch_bounds__(256) void issim_reduce(
    const float* __restrict__ partial, float* __restrict__ out)
{
    const int tid = threadIdx.x;
    float s = 0.f;
    for (int i = tid; i < NB * NP; i += 256) s += partial[i];
#pragma unroll
    for (int d = 32; d > 0; d >>= 1) s += __shfl_down(s, d, 64);
    __shared__ float wsum[4];
    int wid = tid >> 6, lane = tid & 63;
    if (lane == 0) wsum[wid] = s;
    __syncthreads();
    if (tid == 0) out[0] = (wsum[0] + wsum[1] + wsum[2] + wsum[3]) / (float)(NB * NP);
}

extern "C" void kernel_launch(void* const* d_in, const int* in_sizes, int n_in,
                              void* d_out, int out_size, void* d_ws, size_t ws_size,
                              hipStream_t stream) {
    const float* outp = (const float*)d_in[0];   // "output"
    const float* tgt  = (const float*)d_in[1];   // "target"
    const int*   pts  = (const int*)d_in[2];     // "points" [B,P,2]
    float* partial = (float*)d_ws;               // B*P floats
    float* out     = (float*)d_out;

    // Gaussian window (sigma=1.5), computed in double, normalized, cast to fp32.
    GWin gw;
    {
        double raw[NTAP], s = 0.0;
        for (int i = 0; i < NTAP; ++i) {
            double xv = (double)i - (double)(NTAP / 2);
            raw[i] = exp(-(xv * xv) / (2.0 * 1.5 * 1.5));
            s += raw[i];
        }
        for (int i = 0; i < NTAP; ++i) gw.g[i] = (float)(raw[i] / s);
    }

    issim_crops<<<NB * NP, 256, 0, stream>>>(outp, tgt, pts, partial, gw);
    issim_reduce<<<1, 256, 0, stream>>>(partial, out);
}

// Round 15
// 255.589 us; speedup vs baseline: 1.1359x; 1.1359x over previous
//
#include <hip/hip_runtime.h>
#include <math.h>

#define NB    32      // batch
#define NP    100     // points per image
#define IMH   1024
#define IMW   1024
#define CS    32      // crop size
#define OFFS  16
#define NTAP  33
#define C1c   0.0001f // 0.01^2
#define C2c   0.0009f // 0.03^2
#define PSTR  65      // padded staging row stride (words) -> conflict-free

struct GWin { float g[NTAP]; };

// LDS plan (union across phases, separated by barriers):
//   phase 1-2: tp[32][65] (8320 B) + op[32][65] (8320 B)   = 16640 B
//   phase 3-4: vh4[32][32] float4 (16384 B) + vh1[32][32]  = 20480 B
#define SMEM_BYTES 20480

__global__ __launch_bounds__(256) void issim_crops(
    const float* __restrict__ outp,   // [B,1,H,W]
    const float* __restrict__ tgt,    // [B,1,H,W]
    const int*   __restrict__ pts,    // [B,P,2] (y,x)
    float* __restrict__ partial,      // [B*P] per-crop sums
    GWin gw)
{
    __shared__ __align__(16) char smem[SMEM_BYTES];
    __shared__ float wsum[4];
    float  (*tp)[PSTR] = (float (*)[PSTR])smem;
    float  (*op)[PSTR] = (float (*)[PSTR])(smem + CS * PSTR * 4);
    float4 (*vh4)[CS]  = (float4 (*)[CS])smem;
    float  (*vh1)[CS]  = (float (*)[CS])(smem + 16384);

    const int bp = blockIdx.x;            // crop id in [0, B*P)
    const int b  = bp / NP;
    const int y  = pts[bp * 2 + 0];
    const int x  = pts[bp * 2 + 1];
    const float* tb = tgt  + (size_t)b * IMH * IMW;
    const float* ob = outp + (size_t)b * IMH * IMW;
    const int tid = threadIdx.x;

    // ---- Phase 1: stage 32x32 crops into col-padded LDS (zeros in pads) ----
    // All lanes load; 32 consecutive lanes read 32 consecutive floats (128 B).
#pragma unroll
    for (int kk = 0; kk < 4; ++kk) {
        int idx = tid + kk * 256;         // 0..1023
        int r = idx >> 5, c = idx & 31;
        size_t a = (size_t)(y - OFFS + r) * IMW + (x - OFFS + c);
        tp[r][c + OFFS] = tb[a];
        op[r][c + OFFS] = ob[a];
        int cz = (c < OFFS) ? c : (c + 32);   // pad cols 0..15 and 48..63
        tp[r][cz] = 0.f;
        op[r][cz] = 0.f;
    }
    __syncthreads();

    // ---- Phase 2: horizontal pass, register-blocked x4 along j ----
    // thread -> row hr = tid>>3, output cols j0..j0+3. Branch-free (col pads).
    const int hr = tid >> 3;
    const int j0 = (tid & 7) * 4;
    float at[4]  = {0.f, 0.f, 0.f, 0.f};
    float ao[4]  = {0.f, 0.f, 0.f, 0.f};
    float att[4] = {0.f, 0.f, 0.f, 0.f};
    float aoo[4] = {0.f, 0.f, 0.f, 0.f};
    float ato[4] = {0.f, 0.f, 0.f, 0.f};
#pragma unroll
    for (int k = 0; k < 36; ++k) {        // union window of 4 outputs
        float tv = tp[hr][j0 + k];
        float ov = op[hr][j0 + k];
        float tt = tv * tv, oo = ov * ov, to = tv * ov;
#pragma unroll
        for (int m = 0; m < 4; ++m) {
            int ki = k - m;               // compile-time after unroll
            if (ki >= 0 && ki < NTAP) {
                float w = gw.g[ki];
                at[m]  += w * tv;
                ao[m]  += w * ov;
                att[m] += w * tt;
                aoo[m] += w * oo;
                ato[m] += w * to;
            }
        }
    }
    __syncthreads();   // all tp/op reads complete before LDS reuse

    // ---- Phase 3: write horizontal results (float4 + float layout) ----
#pragma unroll
    for (int m = 0; m < 4; ++m) {
        vh4[hr][j0 + m] = make_float4(at[m], ao[m], att[m], aoo[m]);
        vh1[hr][j0 + m] = ato[m];
    }
    __syncthreads();

    // ---- Phase 4: vertical pass (register-blocked x4 along i) + SSIM ----
    // thread -> col vj = tid&31, output rows i0..i0+3. Row pads via cndmask.
    const int vj = tid & 31;
    const int i0 = (tid >> 5) * 4;
    float vt[4]  = {0.f, 0.f, 0.f, 0.f};
    float vo[4]  = {0.f, 0.f, 0.f, 0.f};
    float vtt[4] = {0.f, 0.f, 0.f, 0.f};
    float voo[4] = {0.f, 0.f, 0.f, 0.f};
    float vto[4] = {0.f, 0.f, 0.f, 0.f};
#pragma unroll
    for (int k = 0; k < 36; ++k) {
        int row = i0 + k - OFFS;          // [-16, 47]
        bool rv = (row >= 0) && (row < CS);
        int rc = row & 31;                // always in-bounds read
        float4 h4 = vh4[rc][vj];
        float  h1 = vh1[rc][vj];
        float a0 = rv ? h4.x : 0.f;
        float a1 = rv ? h4.y : 0.f;
        float a2 = rv ? h4.z : 0.f;
        float a3 = rv ? h4.w : 0.f;
        float a4 = rv ? h1   : 0.f;
#pragma unroll
        for (int m = 0; m < 4; ++m) {
            int ki = k - m;
            if (ki >= 0 && ki < NTAP) {
                float w = gw.g[ki];
                vt[m]  += w * a0;
                vo[m]  += w * a1;
                vtt[m] += w * a2;
                voo[m] += w * a3;
                vto[m] += w * a4;
            }
        }
    }

    float lsum = 0.f;
#pragma unroll
    for (int m = 0; m < 4; ++m) {
        float mu1 = vt[m], mu2 = vo[m];
        float mu1s = mu1 * mu1, mu2s = mu2 * mu2, mu12 = mu1 * mu2;
        float s1  = vtt[m] - mu1s;
        float s2  = voo[m] - mu2s;
        float s12 = vto[m] - mu12;
        float num = (2.f * mu12 + C1c) * (2.f * s12 + C2c);
        float den = (mu1s + mu2s + C1c) * (s1 + s2 + C2c);
        lsum += 1.f - num / den;
    }

    // ---- block reduction ----
#pragma unroll
    for (int d = 32; d > 0; d >>= 1) lsum += __shfl_down(lsum, d, 64);
    int wid = tid >> 6, lane = tid & 63;
    if (lane == 0) wsum[wid] = lsum;
    __syncthreads();
    if (tid == 0) partial[bp] = wsum[0] + wsum[1] + wsum[2] + wsum[3];
}

__global__ __launch_bounds__(256) void issim_reduce(
    const float* __restrict__ partial, float* __restrict__ out)
{
    const int tid = threadIdx.x;
    float s = 0.f;
    for (int i = tid; i < NB * NP; i += 256) s += partial[i];
#pragma unroll
    for (int d = 32; d > 0; d >>= 1) s += __shfl_down(s, d, 64);
    __shared__ float wsum[4];
    int wid = tid >> 6, lane = tid & 63;
    if (lane == 0) wsum[wid] = s;
    __syncthreads();
    if (tid == 0) out[0] = (wsum[0] + wsum[1] + wsum[2] + wsum[3]) / (float)(NB * NP);
}

extern "C" void kernel_launch(void* const* d_in, const int* in_sizes, int n_in,
                              void* d_out, int out_size, void* d_ws, size_t ws_size,
                              hipStream_t stream) {
    const float* outp = (const float*)d_in[0];   // "output"
    const float* tgt  = (const float*)d_in[1];   // "target"
    const int*   pts  = (const int*)d_in[2];     // "points" [B,P,2]
    float* partial = (float*)d_ws;               // B*P floats
    float* out     = (float*)d_out;

    // Gaussian window (sigma=1.5), computed in double, normalized, cast to fp32.
    GWin gw;
    {
        double raw[NTAP], s = 0.0;
        for (int i = 0; i < NTAP; ++i) {
            double xv = (double)i - (double)(NTAP / 2);
            raw[i] = exp(-(xv * xv) / (2.0 * 1.5 * 1.5));
            s += raw[i];
        }
        for (int i = 0; i < NTAP; ++i) gw.g[i] = (float)(raw[i] / s);
    }

    issim_crops<<<NB * NP, 256, 0, stream>>>(outp, tgt, pts, partial, gw);
    issim_reduce<<<1, 256, 0, stream>>>(partial, out);
}